// Round 3
// baseline (332.157 us; speedup 1.0000x reference)
//
#include <hip/hip_runtime.h>
#include <hip/hip_bf16.h>
#include <cstdint>
#include <cstddef>

// Problem constants
constexpr int Bb = 4;
constexpr int Tt = 2048;
constexpr int Mm = 1024;
constexpr int Hh = 2048;
constexpr int Ee = 8;
constexpr int Ss = Bb * Tt;   // 8192
constexpr int Cc = 2048;      // capacity per expert

typedef __attribute__((ext_vector_type(4))) float f32x4;
typedef __attribute__((ext_vector_type(8))) short bf16x8;

__device__ inline void load_lds16(const void* g, void* l) {
    __builtin_amdgcn_global_load_lds(
        (const __attribute__((address_space(1))) unsigned int*)g,
        (__attribute__((address_space(3))) unsigned int*)l, 16, 0, 0);
}

// ---------------- w1 (E,M,H) fp32 -> w1t (E,H,M) bf16 (transpose+convert) ----------------
__global__ __launch_bounds__(256) void k_w1t(const float* __restrict__ w1,
                                             __hip_bfloat16* __restrict__ w1t) {
    __shared__ float tile[64][65];
    int e = blockIdx.z, m0 = blockIdx.y * 64, h0 = blockIdx.x * 64;
    int t = threadIdx.x;
    const float* src = w1 + (size_t)e * Mm * Hh;
    #pragma unroll
    for (int i = 0; i < 4; i++) {
        int idx = t + i * 256;            // [0,1024)
        int r = idx >> 4, c4 = idx & 15;  // r: m-row, c4: h-chunk of 4
        float4 v = *(const float4*)(src + (size_t)(m0 + r) * Hh + h0 + c4 * 4);
        tile[r][c4 * 4 + 0] = v.x; tile[r][c4 * 4 + 1] = v.y;
        tile[r][c4 * 4 + 2] = v.z; tile[r][c4 * 4 + 3] = v.w;
    }
    __syncthreads();
    __hip_bfloat16* dst = w1t + (size_t)e * Hh * Mm;
    #pragma unroll
    for (int i = 0; i < 2; i++) {
        int idx = t + i * 256;            // [0,512)
        int r = idx >> 3, c8 = idx & 7;   // r: h-row, c8: m-chunk of 8
        __hip_bfloat16 tmp[8];
        #pragma unroll
        for (int k = 0; k < 8; k++) tmp[k] = __float2bfloat16(tile[c8 * 8 + k][r]);
        uint4 vv; __builtin_memcpy(&vv, tmp, 16);
        *(uint4*)(dst + (size_t)(h0 + r) * Mm + m0 + c8 * 8) = vv;
    }
}

// ---------------- w2sum[e,h] = sum_m w2[e,h,m]; last block: b2sum[e] = sum_m b2[e,m] ----------------
__global__ void k_w2sum(const float* __restrict__ w2, const float* __restrict__ b2,
                        float* __restrict__ w2sum, float* __restrict__ b2sum) {
    int wave = threadIdx.x >> 6, lane = threadIdx.x & 63;
    if (blockIdx.x < Ee * Hh / 4) {
        int r = blockIdx.x * 4 + wave;   // r in [0, E*H)
        const float4* p = (const float4*)(w2 + (size_t)r * Mm);
        float s = 0.f;
        #pragma unroll
        for (int i = 0; i < 4; i++) { float4 v = p[lane + i * 64]; s += v.x + v.y + v.z + v.w; }
        #pragma unroll
        for (int off = 32; off; off >>= 1) s += __shfl_down(s, off);
        if (lane == 0) w2sum[r] = s;
    } else {
        // b2sum: 4 waves x 2 half-waves = 8 experts
        int e = wave * 2 + (lane >> 5);
        int l = lane & 31;
        const float4* p = (const float4*)(b2 + (size_t)e * Mm);
        float s = 0.f;
        #pragma unroll
        for (int i = 0; i < 8; i++) { float4 v = p[l + i * 32]; s += v.x + v.y + v.z + v.w; }
        #pragma unroll
        for (int off = 16; off; off >>= 1) s += __shfl_down(s, off);
        if (l == 0) b2sum[e] = s;
    }
}

// ---------------- gating (one wave per token) + x -> bf16 conversion ----------------
__global__ __launch_bounds__(256) void k_gate(const float* __restrict__ x,
                                              const float* __restrict__ wg,
                                              int* __restrict__ esel, float* __restrict__ gates,
                                              __hip_bfloat16* __restrict__ xbf) {
    int s = (blockIdx.x * 256 + threadIdx.x) >> 6;   // token id
    int lane = threadIdx.x & 63;
    const float4* xr = (const float4*)(x + (size_t)s * Mm);
    const float4* wgr = (const float4*)wg;
    float acc[8];
    #pragma unroll
    for (int e = 0; e < 8; e++) acc[e] = 0.f;
    #pragma unroll
    for (int i = 0; i < 4; i++) {
        float4 xv = xr[lane + i * 64];
        // emit bf16 copy of x
        __hip_bfloat16 tb[4];
        tb[0] = __float2bfloat16(xv.x); tb[1] = __float2bfloat16(xv.y);
        tb[2] = __float2bfloat16(xv.z); tb[3] = __float2bfloat16(xv.w);
        uint2 u; __builtin_memcpy(&u, tb, 8);
        *(uint2*)(xbf + (size_t)s * Mm + (lane + i * 64) * 4) = u;
        int mbase = (lane + i * 64) * 4;
        #pragma unroll
        for (int k = 0; k < 4; k++) {
            int m = mbase + k;
            float xm = (k == 0) ? xv.x : (k == 1) ? xv.y : (k == 2) ? xv.z : xv.w;
            float4 w0 = wgr[m * 2], w1v = wgr[m * 2 + 1];
            acc[0] += xm * w0.x;  acc[1] += xm * w0.y;  acc[2] += xm * w0.z;  acc[3] += xm * w0.w;
            acc[4] += xm * w1v.x; acc[5] += xm * w1v.y; acc[6] += xm * w1v.z; acc[7] += xm * w1v.w;
        }
    }
    #pragma unroll
    for (int off = 32; off; off >>= 1)
        #pragma unroll
        for (int e = 0; e < 8; e++) acc[e] += __shfl_down(acc[e], off);
    if (lane == 0) {
        float mx = acc[0];
        #pragma unroll
        for (int e = 1; e < 8; e++) mx = fmaxf(mx, acc[e]);
        float p[8], se = 0.f;
        #pragma unroll
        for (int e = 0; e < 8; e++) { p[e] = expf(acc[e] - mx); se += p[e]; }
        float inv = 1.f / se;
        #pragma unroll
        for (int e = 0; e < 8; e++) p[e] *= inv;
        int i0 = 0; float v0 = p[0];
        #pragma unroll
        for (int e = 1; e < 8; e++) if (p[e] > v0) { v0 = p[e]; i0 = e; }
        int i1 = -1; float v1 = -1.f;
        #pragma unroll
        for (int e = 0; e < 8; e++) if (e != i0 && p[e] > v1) { v1 = p[e]; i1 = e; }
        float den = v0 + v1 + 1e-9f;
        esel[s] = i0; esel[Ss + s] = i1;
        gates[s] = v0 / den; gates[Ss + s] = v1 / den;
    }
}

// ---------------- positions: parallel 2-phase scan (j-major = linear d) ----------------
__global__ __launch_bounds__(256) void k_posA(const int* __restrict__ esel,
                                              int* __restrict__ lrank, int* __restrict__ blockhist) {
    int b = blockIdx.x, t = threadIdx.x;
    int d = b * 256 + t;
    int e = esel[d];
    int wave = t >> 6, lane = t & 63;
    __shared__ int wh[4][8];
    unsigned long long mymask = 0;
    #pragma unroll
    for (int q = 0; q < 8; q++) {
        unsigned long long m = __ballot(e == q);
        if (q == e) mymask = m;
        if (lane == 0) wh[wave][q] = (int)__popcll(m);
    }
    __syncthreads();
    int prefix = (int)__popcll(mymask & ((1ull << lane) - 1ull));
    for (int w = 0; w < wave; w++) prefix += wh[w][e];
    lrank[d] = prefix;
    if (t < 8) blockhist[b * 8 + t] = wh[0][t] + wh[1][t] + wh[2][t] + wh[3][t];
}

__global__ void k_posB(const int* __restrict__ blockhist, int* __restrict__ blockbase) {
    int q = threadIdx.x;
    if (q < 8) {
        int run = 0;
        for (int b = 0; b < 64; b++) {
            blockbase[b * 8 + q] = run;
            run += blockhist[b * 8 + q];
        }
    }
}

// ---------------- scatter: one block per token, both expert choices ----------------
__global__ __launch_bounds__(128) void k_scatter(const __hip_bfloat16* __restrict__ xbf,
                                                 const int* __restrict__ esel,
                                                 const int* __restrict__ lrank,
                                                 const int* __restrict__ blockbase,
                                                 int* __restrict__ pos,
                                                 __hip_bfloat16* __restrict__ xbuf) {
    int s = blockIdx.x;           // [0, S)
    __shared__ int sp[2], se[2];
    if (threadIdx.x < 2) {
        int d = threadIdx.x * Ss + s;
        int e = esel[d];
        int p = blockbase[(d >> 8) * 8 + e] + lrank[d];
        pos[d] = p; sp[threadIdx.x] = p; se[threadIdx.x] = e;
    }
    __syncthreads();
    int t = threadIdx.x;
    uint4 v = *(const uint4*)(xbf + (size_t)s * Mm + t * 8);
    if (sp[0] < Cc) *(uint4*)(xbuf + ((size_t)se[0] * Cc + sp[0]) * Mm + t * 8) = v;
    if (sp[1] < Cc) *(uint4*)(xbuf + ((size_t)se[1] * Cc + sp[1]) * Mm + t * 8) = v;
}

// ---------------- fused expert GEMM + relu + w2sum reduction ----------------
// BK=64, xor-swizzled LDS chunks (16B granularity) -> conflict-free ds_read_b128,
// while keeping global_load_lds dest = wave-uniform base + lane*16.
__global__ __launch_bounds__(256) void k_gemm(
    const __hip_bfloat16* __restrict__ xbuf, const __hip_bfloat16* __restrict__ w1t,
    const float* __restrict__ b1, const float* __restrict__ w2sum,
    float* __restrict__ rowsum) {
    __shared__ __align__(16) __hip_bfloat16 As[128 * 64];
    __shared__ __align__(16) __hip_bfloat16 Bs[128 * 64];
    int e = blockIdx.y;
    // 4x4 block swizzle: 16 consecutive ids share 4 c-tiles x 4 h-tiles (2 MB working set)
    int bid = blockIdx.x;
    int sq = bid >> 4, in16 = bid & 15;
    int hb = (sq & 3) * 4 + (in16 & 3);
    int cb = (sq >> 2) * 4 + (in16 >> 2);
    int c0 = cb * 128, h0 = hb * 128;
    int t = threadIdx.x;
    int wave = t >> 6, lane = t & 63;
    int wm = wave >> 1, wn = wave & 1;
    int r16 = lane & 15, quad = lane >> 4;
    const __hip_bfloat16* Ab = xbuf + (size_t)e * Cc * Mm;
    const __hip_bfloat16* Bp = w1t + (size_t)e * Hh * Mm;
    f32x4 acc[4][4];
    #pragma unroll
    for (int i = 0; i < 4; i++)
        #pragma unroll
        for (int j = 0; j < 4; j++) acc[i][j] = (f32x4){0.f, 0.f, 0.f, 0.f};

    for (int k0 = 0; k0 < Mm; k0 += 64) {
        #pragma unroll
        for (int p = 0; p < 4; ++p) {
            int ci = p * 256 + t;            // 16B chunk id in [0,1024)
            int row = ci >> 3, qs = ci & 7;
            int q = qs ^ (row & 7);          // xor swizzle (global side)
            load_lds16(Ab + (size_t)(c0 + row) * Mm + k0 + q * 8, As + ci * 8);
            load_lds16(Bp + (size_t)(h0 + row) * Mm + k0 + q * 8, Bs + ci * 8);
        }
        __syncthreads();
        #pragma unroll
        for (int kk = 0; kk < 2; kk++) {
            bf16x8 af[4], bfr[4];
            #pragma unroll
            for (int mi = 0; mi < 4; mi++) {
                int row = wm * 64 + mi * 16 + r16;
                int qx = (kk * 4 + quad) ^ (row & 7);
                af[mi] = *(const bf16x8*)(As + row * 64 + qx * 8);
            }
            #pragma unroll
            for (int ni = 0; ni < 4; ni++) {
                int row = wn * 64 + ni * 16 + r16;
                int qx = (kk * 4 + quad) ^ (row & 7);
                bfr[ni] = *(const bf16x8*)(Bs + row * 64 + qx * 8);
            }
            #pragma unroll
            for (int mi = 0; mi < 4; mi++)
                #pragma unroll
                for (int ni = 0; ni < 4; ni++)
                    acc[mi][ni] = __builtin_amdgcn_mfma_f32_16x16x32_bf16(af[mi], bfr[ni], acc[mi][ni], 0, 0, 0);
        }
        __syncthreads();
    }

    // epilogue: relu(s + b1) * w2sum, reduce over h, atomic into rowsum[e, c]
    float b1v[4], wsv[4];
    #pragma unroll
    for (int ni = 0; ni < 4; ni++) {
        int hg = h0 + wn * 64 + ni * 16 + r16;
        b1v[ni] = b1[e * Hh + hg];
        wsv[ni] = w2sum[e * Hh + hg];
    }
    #pragma unroll
    for (int mi = 0; mi < 4; mi++) {
        #pragma unroll
        for (int r = 0; r < 4; r++) {
            float val = 0.f;
            #pragma unroll
            for (int ni = 0; ni < 4; ni++) {
                float sv = acc[mi][ni][r] + b1v[ni];
                val += fmaxf(sv, 0.f) * wsv[ni];
            }
            #pragma unroll
            for (int off = 1; off < 16; off <<= 1) val += __shfl_xor(val, off);
            if (r16 == 0) {
                int cg = c0 + wm * 64 + mi * 16 + quad * 4 + r;
                atomicAdd(&rowsum[e * Cc + cg], val);
            }
        }
    }
}

// ---------------- combine + per-batch log-softmax over T ----------------
__global__ __launch_bounds__(1024) void k_final(
    const int* __restrict__ esel, const int* __restrict__ pos,
    const float* __restrict__ gates, const float* __restrict__ rowsum,
    const float* __restrict__ b2sum, float* __restrict__ out) {
    int b = blockIdx.x; int t = threadIdx.x;
    __shared__ float red[1024];
    float vv[2];
    #pragma unroll
    for (int i = 0; i < 2; i++) {
        int tok = t + i * 1024;
        int s = b * Tt + tok;
        float acc = 0.f;
        #pragma unroll
        for (int j = 0; j < 2; j++) {
            int d = j * Ss + s;
            int p = pos[d];
            if (p < Cc) {
                int e = esel[d];
                acc += gates[d] * (rowsum[e * Cc + p] + b2sum[e]);
            }
        }
        vv[i] = acc;
    }
    float m = fmaxf(vv[0], vv[1]);
    red[t] = m; __syncthreads();
    for (int st = 512; st; st >>= 1) { if (t < st) red[t] = fmaxf(red[t], red[t + st]); __syncthreads(); }
    float mx = red[0];
    __syncthreads();
    float se = expf(vv[0] - mx) + expf(vv[1] - mx);
    red[t] = se; __syncthreads();
    for (int st = 512; st; st >>= 1) { if (t < st) red[t] += red[t + st]; __syncthreads(); }
    float lse = logf(red[0]);
    #pragma unroll
    for (int i = 0; i < 2; i++) {
        int tok = t + i * 1024;
        out[b * Tt + tok] = vv[i] - mx - lse;
    }
}

extern "C" void kernel_launch(void* const* d_in, const int* in_sizes, int n_in,
                              void* d_out, int out_size, void* d_ws, size_t ws_size,
                              hipStream_t stream) {
    const float* x  = (const float*)d_in[0];
    const float* wg = (const float*)d_in[1];
    const float* w1 = (const float*)d_in[2];
    const float* b1 = (const float*)d_in[3];
    const float* w2 = (const float*)d_in[4];
    const float* b2 = (const float*)d_in[5];
    float* out = (float*)d_out;

    char* ws = (char*)d_ws;
    size_t off = 0;
    auto alloc = [&](size_t bytes) -> void* {
        void* p = ws + off;
        off += (bytes + 255) & ~(size_t)255;
        return p;
    };
    float* w2sum    = (float*)alloc((size_t)Ee * Hh * 4);
    float* b2sum    = (float*)alloc(Ee * 4);
    int*   esel     = (int*)alloc((size_t)2 * Ss * 4);
    int*   lrank    = (int*)alloc((size_t)2 * Ss * 4);
    int*   blockhist= (int*)alloc((size_t)64 * 8 * 4);
    int*   blockbase= (int*)alloc((size_t)64 * 8 * 4);
    int*   pos      = (int*)alloc((size_t)2 * Ss * 4);
    float* gates    = (float*)alloc((size_t)2 * Ss * 4);
    float* rowsum   = (float*)alloc((size_t)Ee * Cc * 4);
    __hip_bfloat16* xbf  = (__hip_bfloat16*)alloc((size_t)Ss * Mm * 2);
    __hip_bfloat16* w1t  = (__hip_bfloat16*)alloc((size_t)Ee * Hh * Mm * 2);
    __hip_bfloat16* xbuf = (__hip_bfloat16*)alloc((size_t)Ee * Cc * Mm * 2);

    hipMemsetAsync(rowsum, 0, (size_t)Ee * Cc * 4, stream);
    k_w1t<<<dim3(Hh / 64, Mm / 64, Ee), 256, 0, stream>>>(w1, w1t);
    k_w2sum<<<Ee * Hh / 4 + 1, 256, 0, stream>>>(w2, b2, w2sum, b2sum);
    k_gate<<<Ss / 4, 256, 0, stream>>>(x, wg, esel, gates, xbf);
    k_posA<<<64, 256, 0, stream>>>(esel, lrank, blockhist);
    k_posB<<<1, 64, 0, stream>>>(blockhist, blockbase);
    k_scatter<<<Ss, 128, 0, stream>>>(xbf, esel, lrank, blockbase, pos, xbuf);
    k_gemm<<<dim3(16 * 16, Ee), 256, 0, stream>>>(xbuf, w1t, b1, w2sum, rowsum);
    k_final<<<Bb, 1024, 0, stream>>>(esel, pos, gates, rowsum, b2sum, out);
}

// Round 4
// 305.567 us; speedup vs baseline: 1.0870x; 1.0870x over previous
//
#include <hip/hip_runtime.h>
#include <hip/hip_bf16.h>
#include <cstdint>
#include <cstddef>

// Problem constants
constexpr int Bb = 4;
constexpr int Tt = 2048;
constexpr int Mm = 1024;
constexpr int Hh = 2048;
constexpr int Ee = 8;
constexpr int Ss = Bb * Tt;   // 8192
constexpr int Cc = 2048;      // capacity per expert

typedef __attribute__((ext_vector_type(4))) float f32x4;
typedef __attribute__((ext_vector_type(8))) short bf16x8;

__device__ inline void load_lds16(const void* g, void* l) {
    __builtin_amdgcn_global_load_lds(
        (const __attribute__((address_space(1))) unsigned int*)g,
        (__attribute__((address_space(3))) unsigned int*)l, 16, 0, 0);
}

// ---------------- fused prep: w1 transpose+cast | w2sum/b2sum | gate + x->bf16 ----------------
// blocks [0,4096): w1 (E,M,H) fp32 -> w1t (E,H,M) bf16
// blocks [4096,8192): w2sum[e,h] = sum_m w2[e,h,m]   block 8192: b2sum
// blocks [8193,10241): gating (one wave per token) + xbf emit
__global__ __launch_bounds__(256) void k_prep(
    const float* __restrict__ w1, const float* __restrict__ w2, const float* __restrict__ b2,
    const float* __restrict__ x, const float* __restrict__ wg,
    __hip_bfloat16* __restrict__ w1t, float* __restrict__ w2sum, float* __restrict__ b2sum,
    int* __restrict__ esel, float* __restrict__ gates, __hip_bfloat16* __restrict__ xbf) {
    int bid = blockIdx.x;
    int t = threadIdx.x;
    if (bid < 4096) {
        // ---- w1 transpose: 64x64 tile; h-idx = bid&31, m-idx = (bid>>5)&15, e = bid>>9
        __shared__ float tile[64][65];
        int e = bid >> 9, m0 = ((bid >> 5) & 15) * 64, h0 = (bid & 31) * 64;
        const float* src = w1 + (size_t)e * Mm * Hh;
        #pragma unroll
        for (int i = 0; i < 4; i++) {
            int idx = t + i * 256;            // [0,1024)
            int r = idx >> 4, c4 = idx & 15;  // r: m-row, c4: h-chunk of 4
            float4 v = *(const float4*)(src + (size_t)(m0 + r) * Hh + h0 + c4 * 4);
            tile[r][c4 * 4 + 0] = v.x; tile[r][c4 * 4 + 1] = v.y;
            tile[r][c4 * 4 + 2] = v.z; tile[r][c4 * 4 + 3] = v.w;
        }
        __syncthreads();
        __hip_bfloat16* dst = w1t + (size_t)e * Hh * Mm;
        #pragma unroll
        for (int i = 0; i < 2; i++) {
            int idx = t + i * 256;            // [0,512)
            int r = idx >> 3, c8 = idx & 7;   // r: h-row, c8: m-chunk of 8
            __hip_bfloat16 tmp[8];
            #pragma unroll
            for (int k = 0; k < 8; k++) tmp[k] = __float2bfloat16(tile[c8 * 8 + k][r]);
            uint4 vv; __builtin_memcpy(&vv, tmp, 16);
            *(uint4*)(dst + (size_t)(h0 + r) * Mm + m0 + c8 * 8) = vv;
        }
    } else if (bid < 8192) {
        // ---- w2sum: 4 rows per block (one per wave)
        int wave = t >> 6, lane = t & 63;
        int r = (bid - 4096) * 4 + wave;   // r in [0, E*H)
        const float4* p = (const float4*)(w2 + (size_t)r * Mm);
        float s = 0.f;
        #pragma unroll
        for (int i = 0; i < 4; i++) { float4 v = p[lane + i * 64]; s += v.x + v.y + v.z + v.w; }
        #pragma unroll
        for (int off = 32; off; off >>= 1) s += __shfl_down(s, off);
        if (lane == 0) w2sum[r] = s;
    } else if (bid == 8192) {
        // ---- b2sum: 4 waves x 2 half-waves = 8 experts
        int wave = t >> 6, lane = t & 63;
        int e = wave * 2 + (lane >> 5);
        int l = lane & 31;
        const float4* p = (const float4*)(b2 + (size_t)e * Mm);
        float s = 0.f;
        #pragma unroll
        for (int i = 0; i < 8; i++) { float4 v = p[l + i * 32]; s += v.x + v.y + v.z + v.w; }
        #pragma unroll
        for (int off = 16; off; off >>= 1) s += __shfl_down(s, off);
        if (l == 0) b2sum[e] = s;
    } else {
        // ---- gating: one wave per token + bf16 emit
        int gb = bid - 8193;
        int s = (gb * 256 + t) >> 6;   // token id
        int lane = t & 63;
        const float4* xr = (const float4*)(x + (size_t)s * Mm);
        const float4* wgr = (const float4*)wg;
        float acc[8];
        #pragma unroll
        for (int e = 0; e < 8; e++) acc[e] = 0.f;
        #pragma unroll
        for (int i = 0; i < 4; i++) {
            float4 xv = xr[lane + i * 64];
            __hip_bfloat16 tb[4];
            tb[0] = __float2bfloat16(xv.x); tb[1] = __float2bfloat16(xv.y);
            tb[2] = __float2bfloat16(xv.z); tb[3] = __float2bfloat16(xv.w);
            uint2 u; __builtin_memcpy(&u, tb, 8);
            *(uint2*)(xbf + (size_t)s * Mm + (lane + i * 64) * 4) = u;
            int mbase = (lane + i * 64) * 4;
            #pragma unroll
            for (int k = 0; k < 4; k++) {
                int m = mbase + k;
                float xm = (k == 0) ? xv.x : (k == 1) ? xv.y : (k == 2) ? xv.z : xv.w;
                float4 w0 = wgr[m * 2], w1v = wgr[m * 2 + 1];
                acc[0] += xm * w0.x;  acc[1] += xm * w0.y;  acc[2] += xm * w0.z;  acc[3] += xm * w0.w;
                acc[4] += xm * w1v.x; acc[5] += xm * w1v.y; acc[6] += xm * w1v.z; acc[7] += xm * w1v.w;
            }
        }
        #pragma unroll
        for (int off = 32; off; off >>= 1)
            #pragma unroll
            for (int e = 0; e < 8; e++) acc[e] += __shfl_down(acc[e], off);
        if (lane == 0) {
            float mx = acc[0];
            #pragma unroll
            for (int e = 1; e < 8; e++) mx = fmaxf(mx, acc[e]);
            float p[8], se = 0.f;
            #pragma unroll
            for (int e = 0; e < 8; e++) { p[e] = expf(acc[e] - mx); se += p[e]; }
            float inv = 1.f / se;
            #pragma unroll
            for (int e = 0; e < 8; e++) p[e] *= inv;
            int i0 = 0; float v0 = p[0];
            #pragma unroll
            for (int e = 1; e < 8; e++) if (p[e] > v0) { v0 = p[e]; i0 = e; }
            int i1 = -1; float v1 = -1.f;
            #pragma unroll
            for (int e = 0; e < 8; e++) if (e != i0 && p[e] > v1) { v1 = p[e]; i1 = e; }
            float den = v0 + v1 + 1e-9f;
            esel[s] = i0; esel[Ss + s] = i1;
            gates[s] = v0 / den; gates[Ss + s] = v1 / den;
        }
    }
}

// ---------------- positions: parallel 2-phase scan (j-major = linear d) ----------------
__global__ __launch_bounds__(256) void k_posA(const int* __restrict__ esel,
                                              int* __restrict__ lrank, int* __restrict__ blockhist) {
    int b = blockIdx.x, t = threadIdx.x;
    int d = b * 256 + t;
    int e = esel[d];
    int wave = t >> 6, lane = t & 63;
    __shared__ int wh[4][8];
    unsigned long long mymask = 0;
    #pragma unroll
    for (int q = 0; q < 8; q++) {
        unsigned long long m = __ballot(e == q);
        if (q == e) mymask = m;
        if (lane == 0) wh[wave][q] = (int)__popcll(m);
    }
    __syncthreads();
    int prefix = (int)__popcll(mymask & ((1ull << lane) - 1ull));
    for (int w = 0; w < wave; w++) prefix += wh[w][e];
    lrank[d] = prefix;
    if (t < 8) blockhist[b * 8 + t] = wh[0][t] + wh[1][t] + wh[2][t] + wh[3][t];
}

__global__ void k_posB(const int* __restrict__ blockhist, int* __restrict__ blockbase) {
    int q = threadIdx.x;
    if (q < 8) {
        int run = 0;
        for (int b = 0; b < 64; b++) {
            blockbase[b * 8 + q] = run;
            run += blockhist[b * 8 + q];
        }
    }
}

// ---------------- finalize positions + build inverse index srcidx[e][c] = token ----------------
__global__ __launch_bounds__(256) void k_sidx(const int* __restrict__ esel,
                                              const int* __restrict__ lrank,
                                              const int* __restrict__ blockbase,
                                              int* __restrict__ pos, int* __restrict__ srcidx) {
    int d = blockIdx.x * 256 + threadIdx.x;
    int e = esel[d];
    int p = blockbase[(d >> 8) * 8 + e] + lrank[d];
    pos[d] = p;
    if (p < Cc) srcidx[e * Cc + p] = d & (Ss - 1);
}

// ---------------- fused expert GEMM (A gathered via srcidx) + relu + w2sum reduction ----------------
// Round-2 structure: BK=32, unpadded LDS stride 32 (2-way alias = free), global_load_lds w=16.
__global__ __launch_bounds__(256) void k_gemm(
    const __hip_bfloat16* __restrict__ xbf, const int* __restrict__ srcidx,
    const __hip_bfloat16* __restrict__ w1t,
    const float* __restrict__ b1, const float* __restrict__ w2sum,
    float* __restrict__ rowsum) {
    __shared__ __align__(16) __hip_bfloat16 As[128 * 32];
    __shared__ __align__(16) __hip_bfloat16 Bs[128 * 32];
    int e = blockIdx.y;
    // 4x4 block swizzle: 16 consecutive ids share 4 c-tiles x 4 h-tiles (2 MB working set)
    int bid = blockIdx.x;
    int sq = bid >> 4, in16 = bid & 15;
    int hb = (sq & 3) * 4 + (in16 & 3);
    int cb = (sq >> 2) * 4 + (in16 >> 2);
    int c0 = cb * 128, h0 = hb * 128;
    int t = threadIdx.x;
    int wave = t >> 6, lane = t & 63;
    int wm = wave >> 1, wn = wave & 1;
    int r16 = lane & 15, quad = lane >> 4;
    // A gather: chunk ci = p*256 + t -> row = p*64 + (t>>2), q = t&3
    int rq = t >> 2, q = t & 3;
    int s0 = srcidx[e * Cc + c0 + rq];
    int s1 = srcidx[e * Cc + c0 + 64 + rq];
    const __hip_bfloat16* a0 = xbf + (size_t)s0 * Mm + q * 8;
    const __hip_bfloat16* a1 = xbf + (size_t)s1 * Mm + q * 8;
    const __hip_bfloat16* Bp = w1t + (size_t)e * Hh * Mm;
    const __hip_bfloat16* b0 = Bp + (size_t)(h0 + rq) * Mm + q * 8;
    const __hip_bfloat16* b1p = Bp + (size_t)(h0 + 64 + rq) * Mm + q * 8;
    f32x4 acc[4][4];
    #pragma unroll
    for (int i = 0; i < 4; i++)
        #pragma unroll
        for (int j = 0; j < 4; j++) acc[i][j] = (f32x4){0.f, 0.f, 0.f, 0.f};

    for (int k0 = 0; k0 < Mm; k0 += 32) {
        load_lds16(a0 + k0, As + t * 8);
        load_lds16(a1 + k0, As + (256 + t) * 8);
        load_lds16(b0 + k0, Bs + t * 8);
        load_lds16(b1p + k0, Bs + (256 + t) * 8);
        __syncthreads();
        bf16x8 af[4], bfr[4];
        #pragma unroll
        for (int mi = 0; mi < 4; mi++)
            af[mi] = *(const bf16x8*)(As + (wm * 64 + mi * 16 + r16) * 32 + quad * 8);
        #pragma unroll
        for (int ni = 0; ni < 4; ni++)
            bfr[ni] = *(const bf16x8*)(Bs + (wn * 64 + ni * 16 + r16) * 32 + quad * 8);
        #pragma unroll
        for (int mi = 0; mi < 4; mi++)
            #pragma unroll
            for (int ni = 0; ni < 4; ni++)
                acc[mi][ni] = __builtin_amdgcn_mfma_f32_16x16x32_bf16(af[mi], bfr[ni], acc[mi][ni], 0, 0, 0);
        __syncthreads();
    }

    // epilogue: relu(s + b1) * w2sum, reduce over h, atomic into rowsum[e, c]
    float b1v[4], wsv[4];
    #pragma unroll
    for (int ni = 0; ni < 4; ni++) {
        int hg = h0 + wn * 64 + ni * 16 + r16;
        b1v[ni] = b1[e * Hh + hg];
        wsv[ni] = w2sum[e * Hh + hg];
    }
    #pragma unroll
    for (int mi = 0; mi < 4; mi++) {
        #pragma unroll
        for (int r = 0; r < 4; r++) {
            float val = 0.f;
            #pragma unroll
            for (int ni = 0; ni < 4; ni++) {
                float sv = acc[mi][ni][r] + b1v[ni];
                val += fmaxf(sv, 0.f) * wsv[ni];
            }
            #pragma unroll
            for (int off = 1; off < 16; off <<= 1) val += __shfl_xor(val, off);
            if (r16 == 0) {
                int cg = c0 + wm * 64 + mi * 16 + quad * 4 + r;
                atomicAdd(&rowsum[e * Cc + cg], val);
            }
        }
    }
}

// ---------------- combine + per-batch log-softmax over T ----------------
__global__ __launch_bounds__(1024) void k_final(
    const int* __restrict__ esel, const int* __restrict__ pos,
    const float* __restrict__ gates, const float* __restrict__ rowsum,
    const float* __restrict__ b2sum, float* __restrict__ out) {
    int b = blockIdx.x; int t = threadIdx.x;
    __shared__ float red[1024];
    float vv[2];
    #pragma unroll
    for (int i = 0; i < 2; i++) {
        int tok = t + i * 1024;
        int s = b * Tt + tok;
        float acc = 0.f;
        #pragma unroll
        for (int j = 0; j < 2; j++) {
            int d = j * Ss + s;
            int p = pos[d];
            if (p < Cc) {
                int e = esel[d];
                acc += gates[d] * (rowsum[e * Cc + p] + b2sum[e]);
            }
        }
        vv[i] = acc;
    }
    float m = fmaxf(vv[0], vv[1]);
    red[t] = m; __syncthreads();
    for (int st = 512; st; st >>= 1) { if (t < st) red[t] = fmaxf(red[t], red[t + st]); __syncthreads(); }
    float mx = red[0];
    __syncthreads();
    float se = expf(vv[0] - mx) + expf(vv[1] - mx);
    red[t] = se; __syncthreads();
    for (int st = 512; st; st >>= 1) { if (t < st) red[t] += red[t + st]; __syncthreads(); }
    float lse = logf(red[0]);
    #pragma unroll
    for (int i = 0; i < 2; i++) {
        int tok = t + i * 1024;
        out[b * Tt + tok] = vv[i] - mx - lse;
    }
}

extern "C" void kernel_launch(void* const* d_in, const int* in_sizes, int n_in,
                              void* d_out, int out_size, void* d_ws, size_t ws_size,
                              hipStream_t stream) {
    const float* x  = (const float*)d_in[0];
    const float* wg = (const float*)d_in[1];
    const float* w1 = (const float*)d_in[2];
    const float* b1 = (const float*)d_in[3];
    const float* w2 = (const float*)d_in[4];
    const float* b2 = (const float*)d_in[5];
    float* out = (float*)d_out;

    char* ws = (char*)d_ws;
    size_t off = 0;
    auto alloc = [&](size_t bytes) -> void* {
        void* p = ws + off;
        off += (bytes + 255) & ~(size_t)255;
        return p;
    };
    // rowsum + srcidx adjacent -> single memset
    float* rowsum   = (float*)alloc((size_t)Ee * Cc * 4 + (size_t)Ee * Cc * 4);
    int*   srcidx   = (int*)(rowsum + (size_t)Ee * Cc);
    float* w2sum    = (float*)alloc((size_t)Ee * Hh * 4);
    float* b2sum    = (float*)alloc(Ee * 4);
    int*   esel     = (int*)alloc((size_t)2 * Ss * 4);
    int*   lrank    = (int*)alloc((size_t)2 * Ss * 4);
    int*   blockhist= (int*)alloc((size_t)64 * 8 * 4);
    int*   blockbase= (int*)alloc((size_t)64 * 8 * 4);
    int*   pos      = (int*)alloc((size_t)2 * Ss * 4);
    float* gates    = (float*)alloc((size_t)2 * Ss * 4);
    __hip_bfloat16* xbf = (__hip_bfloat16*)alloc((size_t)Ss * Mm * 2);
    __hip_bfloat16* w1t = (__hip_bfloat16*)alloc((size_t)Ee * Hh * Mm * 2);

    hipMemsetAsync(rowsum, 0, (size_t)2 * Ee * Cc * 4, stream);
    k_prep<<<10241, 256, 0, stream>>>(w1, w2, b2, x, wg, w1t, w2sum, b2sum, esel, gates, xbf);
    k_posA<<<64, 256, 0, stream>>>(esel, lrank, blockhist);
    k_posB<<<1, 64, 0, stream>>>(blockhist, blockbase);
    k_sidx<<<64, 256, 0, stream>>>(esel, lrank, blockbase, pos, srcidx);
    k_gemm<<<dim3(16 * 16, Ee), 256, 0, stream>>>(xbf, srcidx, w1t, b1, w2sum, rowsum);
    k_final<<<Bb, 1024, 0, stream>>>(esel, pos, gates, rowsum, b2sum, out);
}